// Round 1
// 835.033 us; speedup vs baseline: 1.0241x; 1.0241x over previous
//
#include <hip/hip_runtime.h>
#include <hip/hip_bf16.h>

#define NTOK 32768
#define KEMB 4096
#define DDIM 256
#define DECAYF 0.99f
#define EPSF 1e-5f
#define KSPLIT 256          // hi-only fp16: Xh . Ch, error handled by flag+refine
#define FLAG_THETA 0.09f    // ~5 sigma of hi-only distance-diff noise (0.018)
#define PRUNE_MARGIN 0.25f  // 2*theta + 6*sigma error bound for chunk pruning

// ---------------- workspace layout (BYTE offsets) ----------------
#define B_AHAT  0ull          // 32768*256 f16 = 16777216 B  Xh
#define B_BHAT  16777216ull   // 4096*256 f16  = 2097152 B   Ch
#define B_PART  18874368ull   // 32768*64 float4 = 33554432 B per-64col-chunk (b1,b2,idx)
#define B_CE    52428800ull   // 4096 f32
#define B_CNTI  52445184ull   // 4096 int: integer counts (atomic slot counters)
#define B_CSP   52461568ull   // 4096 f32: cs_pre
#define B_OFFS  52477952ull   // 4096 int: CSR offsets
#define B_NPTR  52494336ull   // f32 n ; +4 int flagCount
#define B_TIDX  52494400ull   // 32768 int: per-token argmin
#define B_FLIST 52625472ull   // 32768 int: flagged tokens
#define B_SLOT  52756544ull   // 32768 int: slot of token within its cluster
#define B_TLIST 52887616ull   // 32768 int: CSR token list
#define B_DW    53018688ull   // 4096*256 f32 = 4194304 B segment sums
// total ~57.2 MB

// ---------------- output layout (float offsets) ----------------
#define OFF_Q  0ull                 // quantized  [32768,256]
#define OFF_E  8388608ull           // encodings  [32768,4096]
#define OFF_CB 142606336ull         // new_codebook [4096,256]
#define OFF_W  143654912ull         // new_ema_w    [4096,256]
#define OFF_CS 144703488ull         // cs [4096]

typedef __attribute__((ext_vector_type(8))) _Float16 f16x8;
typedef __attribute__((ext_vector_type(4))) _Float16 f16x4;
typedef __attribute__((ext_vector_type(4))) float f32x4;

// ---- plain coalesced fp32 -> fp16 cast (X only) ----
__global__ __launch_bounds__(256) void cast16_kernel(const float* __restrict__ src,
                                                     _Float16* __restrict__ dst) {
    size_t gid = (size_t)blockIdx.x * 256 + threadIdx.x;
    const float* sp = src + gid * 8;
    f16x8 v;
    #pragma unroll
    for (int t = 0; t < 8; ++t) v[t] = (_Float16)sp[t];
    *(f16x8*)(dst + gid * 8) = v;
}

// ---- fused codebook cast + per-cluster squared norms: one wave per row.
// Reads cbg once (f32), writes Bhat (f16) + ce (f32). Replaces cast16(cb)+ce.
__global__ __launch_bounds__(256) void castcb_ce_kernel(const float* __restrict__ cb,
                                                        _Float16* __restrict__ Bhat,
                                                        float* __restrict__ ce) {
    int k = blockIdx.x * 4 + (threadIdx.x >> 6);
    int lane = threadIdx.x & 63;
    float4 v = *(const float4*)(cb + (size_t)k * DDIM + lane * 4);
    f16x4 h;
    h[0] = (_Float16)v.x; h[1] = (_Float16)v.y;
    h[2] = (_Float16)v.z; h[3] = (_Float16)v.w;
    *(f16x4*)(Bhat + (size_t)k * DDIM + lane * 4) = h;
    float s = v.x * v.x + v.y * v.y + v.z * v.z + v.w * v.w;
    #pragma unroll
    for (int o = 32; o > 0; o >>= 1) s += __shfl_down(s, o);
    if (lane == 0) ce[k] = s;
}

// ---- fp16 MFMA GEMM (M=32768, N=4096, K=256) with fused per-row argmin.
// R3-validated structure: 128x128 tile, BK=64, global_load_lds width-16,
// XOR-swizzled chunk staging -> conflict-free ds_read_b128.
// T1: XCD-aware bijective chunk remap (8192 blocks % 8 == 0) so the 32
// consecutive blocks sharing one A-tile land on ONE XCD's L2 instead of 8.
__global__ __launch_bounds__(256) void gemm_argmin_kernel(
        const _Float16* __restrict__ Ahat,
        const _Float16* __restrict__ Bhat,
        const float* __restrict__ ceg,
        float4* __restrict__ part) {
    __shared__ _Float16 As[128 * 64];   // 16 KB
    __shared__ _Float16 Bs[128 * 64];   // 16 KB
    const int tid  = threadIdx.x;
    const int lane = tid & 63;
    const int wave = tid >> 6;
    const int wm = wave >> 1, wn = wave & 1;  // 2x2 wave grid, 64x64 per wave

    // XCD swizzle: linear id -> contiguous 1024-block chunk per XCD.
    int lin = blockIdx.y * 32 + blockIdx.x;
    lin = (lin & 7) * 1024 + (lin >> 3);      // bijective: 8192 = 8 * 1024
    const int nb = lin & 31, mb = lin >> 5;   // nb fast: A-tile sharers adjacent

    const int col = lane & 15, q = lane >> 4;
    const int cswz = q ^ (col & 7);           // reader chunk swizzle base

    const int srow = tid >> 3;
    const int sswz = (tid & 7) ^ (srow & 7);
    const _Float16* ag = Ahat + (size_t)(mb * 128 + srow) * KSPLIT + sswz * 8;
    const _Float16* bg = Bhat + (size_t)(nb * 128 + srow) * KSPLIT + sswz * 8;

    f32x4 zero = {0.f, 0.f, 0.f, 0.f};
    f32x4 acc[4][4];
    #pragma unroll
    for (int i = 0; i < 4; ++i)
        #pragma unroll
        for (int j = 0; j < 4; ++j) acc[i][j] = zero;

    for (int kt = 0; kt < KSPLIT / 64; ++kt) {
        __syncthreads();
        #pragma unroll
        for (int n = 0; n < 4; ++n) {
            __builtin_amdgcn_global_load_lds(
                (const __attribute__((address_space(1))) void*)(ag + (size_t)n * 32 * KSPLIT + kt * 64),
                (__attribute__((address_space(3))) void*)(As + n * 2048 + tid * 8), 16, 0, 0);
            __builtin_amdgcn_global_load_lds(
                (const __attribute__((address_space(1))) void*)(bg + (size_t)n * 32 * KSPLIT + kt * 64),
                (__attribute__((address_space(3))) void*)(Bs + n * 2048 + tid * 8), 16, 0, 0);
        }
        __syncthreads();

        const f16x8* Av = (const f16x8*)As;
        const f16x8* Bv = (const f16x8*)Bs;
        #pragma unroll
        for (int ks = 0; ks < 2; ++ks) {
            f16x8 a[4], b[4];
            #pragma unroll
            for (int i = 0; i < 4; ++i)
                a[i] = Av[(wm * 64 + i * 16 + col) * 8 + (cswz ^ (ks * 4))];
            #pragma unroll
            for (int j = 0; j < 4; ++j)
                b[j] = Bv[(wn * 64 + j * 16 + col) * 8 + (cswz ^ (ks * 4))];
            #pragma unroll
            for (int i = 0; i < 4; ++i)
                #pragma unroll
                for (int j = 0; j < 4; ++j)
                    acc[i][j] = __builtin_amdgcn_mfma_f32_16x16x32_f16(a[i], b[j], acc[i][j], 0, 0, 0);
        }
    }

    // epilogue: s = ||c||^2 - 2*dot. C/D layout: col = lane&15, row = q*4+reg.
    float ce_j[4];
    #pragma unroll
    for (int j = 0; j < 4; ++j) ce_j[j] = ceg[nb * 128 + wn * 64 + j * 16 + col];

    #pragma unroll
    for (int i = 0; i < 4; ++i) {
        #pragma unroll
        for (int r = 0; r < 4; ++r) {
            float b1 = 3.4e38f, b2 = 3.4e38f;
            int i1 = 0x7fffffff;
            #pragma unroll
            for (int j = 0; j < 4; ++j) {
                float s = ce_j[j] - 2.0f * acc[i][j][r];
                int n = nb * 128 + wn * 64 + j * 16 + col;
                if (s < b1) { b2 = b1; b1 = s; i1 = n; }
                else if (s < b2) { b2 = s; }
            }
            #pragma unroll
            for (int m = 1; m < 16; m <<= 1) {
                float ob1 = __shfl_xor(b1, m, 16);
                float ob2 = __shfl_xor(b2, m, 16);
                int   oi  = __shfl_xor(i1, m, 16);
                bool take = (ob1 < b1) || (ob1 == b1 && oi < i1);
                float nb2 = take ? fminf(b1, ob2) : fminf(b2, ob1);
                if (take) { b1 = ob1; i1 = oi; }
                b2 = nb2;
            }
            if (col == i * 4 + r) {   // unique writer lane per (q,i,r)
                int mrow = mb * 128 + wm * 64 + i * 16 + q * 4 + r;
                float4 p;
                p.x = b1; p.y = b2; p.z = __int_as_float(i1); p.w = 0.0f;
                part[(size_t)mrow * 64 + nb * 2 + wn] = p;
            }
        }
    }
}

// ---- merge 64 column-chunk partials per row; flag near-ties ----
__global__ __launch_bounds__(256) void argmin_reduce_kernel(
        const float4* __restrict__ part,
        int* __restrict__ tokIdx,
        int* __restrict__ flist,
        int* __restrict__ flagCount) {
    int row = blockIdx.x * 4 + (threadIdx.x >> 6);
    int lane = threadIdx.x & 63;
    float4 p = part[(size_t)row * 64 + lane];
    float b1 = p.x, b2 = p.y;
    int i1 = __float_as_int(p.z);
    #pragma unroll
    for (int m = 1; m < 64; m <<= 1) {
        float ob1 = __shfl_xor(b1, m);
        float ob2 = __shfl_xor(b2, m);
        int   oi  = __shfl_xor(i1, m);
        bool take = (ob1 < b1) || (ob1 == b1 && oi < i1);
        float nb2 = take ? fminf(b1, ob2) : fminf(b2, ob1);
        if (take) { b1 = ob1; i1 = oi; }
        b2 = nb2;
    }
    if (lane == 0) {
        tokIdx[row] = i1;
        if (b2 - b1 < FLAG_THETA) {
            int slot = atomicAdd(flagCount, 1);
            flist[slot] = row;
        }
    }
}

// ---- chunk-pruned fp64 refine: one wave per flagged token. ----
__global__ __launch_bounds__(256) void refine_kernel(const float* __restrict__ xg,
                                                     const float* __restrict__ cb,
                                                     const float4* __restrict__ part,
                                                     int* __restrict__ tokIdx,
                                                     const int* __restrict__ flagList,
                                                     const int* __restrict__ flagCount) {
    int nf = *flagCount;
    int lane = threadIdx.x & 63;
    int wid = (blockIdx.x * 256 + threadIdx.x) >> 6;
    int nw = (gridDim.x * 256) >> 6;
    for (int f = wid; f < nf; f += nw) {
        int tok = flagList[f];
        float cb1 = part[(size_t)tok * 64 + lane].x;
        float b1 = cb1;
        #pragma unroll
        for (int m = 1; m < 64; m <<= 1) b1 = fminf(b1, __shfl_xor(b1, m));
        unsigned long long mask = __ballot(cb1 <= b1 + PRUNE_MARGIN);
        double best = 1e300;
        int bi = 0x7fffffff;
        const float* xr = xg + (size_t)tok * DDIM;
        while (mask) {
            int c = __ffsll(mask) - 1;
            mask &= mask - 1;
            int k = c * 64 + lane;
            const float* e = cb + (size_t)k * DDIM;
            double s = 0.0;
            for (int d4 = 0; d4 < DDIM / 4; ++d4) {
                float4 e4 = *(const float4*)(e + d4 * 4);
                float4 x4 = *(const float4*)(xr + d4 * 4);
                double e0 = (double)e4.x, e1 = (double)e4.y;
                double e2 = (double)e4.z, e3 = (double)e4.w;
                s += e0 * (e0 - 2.0 * (double)x4.x) + e1 * (e1 - 2.0 * (double)x4.y)
                   + e2 * (e2 - 2.0 * (double)x4.z) + e3 * (e3 - 2.0 * (double)x4.w);
            }
            if (s < best || (s == best && k < bi)) { best = s; bi = k; }
        }
        #pragma unroll
        for (int m = 1; m < 64; m <<= 1) {
            double ob = __shfl_xor(best, m);
            int   oi  = __shfl_xor(bi, m);
            if (ob < best || (ob == best && oi < bi)) { best = ob; bi = oi; }
        }
        if (lane == 0) tokIdx[tok] = bi;
    }
}

// ---- per-token finalize: one wave per token. Fuses
//   (a) tokslot: slotOf[t] = atomicAdd(countsI[k]) (lane 0)
//   (b) enc one-hot: single 4B store (enc pre-zeroed by hipMemsetAsync)
//   (c) quant row gather-copy (64 lanes x float4, cb is L2-resident)
__global__ __launch_bounds__(256) void finalize_kernel(const float* __restrict__ cb,
                                                       const int* __restrict__ tokIdx,
                                                       int* __restrict__ countsI,
                                                       int* __restrict__ slotOf,
                                                       float* __restrict__ quant,
                                                       float* __restrict__ enc) {
    int t = blockIdx.x * 4 + (threadIdx.x >> 6);
    int lane = threadIdx.x & 63;
    int k = tokIdx[t];
    if (lane == 0) {
        slotOf[t] = atomicAdd(countsI + k, 1);
        enc[(size_t)t * KEMB + k] = 1.0f;
    }
    float4 e = *(const float4*)(cb + (size_t)k * DDIM + lane * 4);
    *(float4*)(quant + (size_t)t * DDIM + lane * 4) = e;
}

// ---- CSR pass 2 + cs: single block. Exclusive scan of countsI -> offs,
// cs_pre = ema_cs*decay + (1-decay)*counts, n = sum(cs_pre) (plain store).
__global__ __launch_bounds__(256) void scan_cs_kernel(const int* __restrict__ countsI,
                                                      const float* __restrict__ ema_cs,
                                                      int* __restrict__ offs,
                                                      float* __restrict__ cs_pre,
                                                      float* __restrict__ nptr) {
    __shared__ int part[256];
    __shared__ float npart[256];
    __shared__ int pref[257];
    int tid = threadIdx.x;
    int local[16];
    int s = 0;
    float ns = 0.0f;
    #pragma unroll
    for (int i = 0; i < 16; ++i) {
        int c = countsI[tid * 16 + i];
        local[i] = c;
        s += c;
        float csp = ema_cs[tid * 16 + i] * DECAYF + (1.0f - DECAYF) * (float)c;
        cs_pre[tid * 16 + i] = csp;
        ns += csp;
    }
    part[tid] = s;
    npart[tid] = ns;
    __syncthreads();
    if (tid == 0) {
        pref[0] = 0;
        float nn = 0.0f;
        for (int i = 0; i < 256; ++i) {
            pref[i + 1] = pref[i] + part[i];
            nn += npart[i];
        }
        nptr[0] = nn;
    }
    __syncthreads();
    int run = pref[tid];
    #pragma unroll
    for (int i = 0; i < 16; ++i) { offs[tid * 16 + i] = run; run += local[i]; }
}

// ---- CSR pass 3: fill token list (no atomics) ----
__global__ __launch_bounds__(256) void filllist_kernel(const int* __restrict__ tokIdx,
                                                       const int* __restrict__ offs,
                                                       const int* __restrict__ slotOf,
                                                       int* __restrict__ tlist) {
    int t = blockIdx.x * 256 + threadIdx.x;
    int k = tokIdx[t];
    tlist[offs[k] + slotOf[t]] = t;
}

// ---- balanced segmented dw reduction over the CSR list ----
#define SEG_CHUNK 32
__global__ __launch_bounds__(256) void segdw_kernel(const float* __restrict__ xg,
                                                    const int* __restrict__ tlist,
                                                    const int* __restrict__ tokIdx,
                                                    float* __restrict__ dw) {
    int tid = threadIdx.x;
    int s0 = blockIdx.x * SEG_CHUNK;
    float acc = 0.0f;
    int curk = -1;
    for (int s = s0; s < s0 + SEG_CHUNK; ++s) {
        int t = tlist[s];
        int k = tokIdx[t];
        if (k != curk) {
            if (curk >= 0) atomicAdd(dw + (size_t)curk * DDIM + tid, acc);
            acc = 0.0f;
            curk = k;
        }
        acc += xg[(size_t)t * DDIM + tid];
    }
    if (curk >= 0) atomicAdd(dw + (size_t)curk * DDIM + tid, acc);
}

// ---- epilogue: new_ema_w, laplace-smoothed cs, new_codebook ----
__global__ __launch_bounds__(256) void epi_kernel(const float* __restrict__ ema_w,
                                                  const float* __restrict__ dw,
                                                  const float* __restrict__ cs_pre,
                                                  const float* __restrict__ nptr,
                                                  float* __restrict__ new_cb,
                                                  float* __restrict__ new_w,
                                                  float* __restrict__ cs_out) {
    int gid = blockIdx.x * 256 + threadIdx.x;   // 0 .. 1048575
    int k = gid >> 8, d = gid & 255;
    float n = *nptr;
    float csp = cs_pre[k];
    float cs = (csp + EPSF) / (n + (float)KEMB * EPSF) * n;
    float w = ema_w[gid] * DECAYF + (1.0f - DECAYF) * dw[gid];
    new_w[gid] = w;
    new_cb[gid] = w / cs;
    if (d == 0) cs_out[k] = cs;
}

extern "C" void kernel_launch(void* const* d_in, const int* in_sizes, int n_in,
                              void* d_out, int out_size, void* d_ws, size_t ws_size,
                              hipStream_t stream) {
    const float* xg     = (const float*)d_in[0];   // [32768,256]
    const float* cbg    = (const float*)d_in[1];   // [4096,256]
    const float* ema_w  = (const float*)d_in[2];   // [4096,256]
    const float* ema_cs = (const float*)d_in[3];   // [4096]

    float* out = (float*)d_out;
    unsigned char* wsb = (unsigned char*)d_ws;

    float* quant  = out + OFF_Q;
    float* enc    = out + OFF_E;
    float* new_cb = out + OFF_CB;
    float* new_w  = out + OFF_W;
    float* cs_out = out + OFF_CS;

    _Float16* Ahat = (_Float16*)(wsb + B_AHAT);
    _Float16* Bhat = (_Float16*)(wsb + B_BHAT);
    float4* part   = (float4*)(wsb + B_PART);
    float* ce      = (float*)(wsb + B_CE);
    int*   countsI = (int*)(wsb + B_CNTI);
    float* cs_pre  = (float*)(wsb + B_CSP);
    int*   offs    = (int*)(wsb + B_OFFS);
    float* nptr    = (float*)(wsb + B_NPTR);
    int*   flagCnt = (int*)(wsb + B_NPTR + 4);
    int*   tokIdx  = (int*)(wsb + B_TIDX);
    int*   flist   = (int*)(wsb + B_FLIST);
    int*   slotOf  = (int*)(wsb + B_SLOT);
    int*   tlist   = (int*)(wsb + B_TLIST);
    float* dw      = (float*)(wsb + B_DW);

    // zero-init (d_out / d_ws are poisoned with 0xAA before every call).
    // enc zeroed by the fill engine (~6.3 TB/s measured on this part);
    // finalize_kernel then writes only the 32768 one-hot elements.
    hipMemsetAsync(enc, 0, (size_t)NTOK * KEMB * sizeof(float), stream);
    hipMemsetAsync(countsI, 0, KEMB * sizeof(int), stream);
    hipMemsetAsync(nptr, 0, 8, stream);                        // n + flagCount
    hipMemsetAsync(dw, 0, (size_t)KEMB * DDIM * sizeof(float), stream);

    cast16_kernel<<<(NTOK * DDIM / 8) / 256, 256, 0, stream>>>(xg, Ahat);
    castcb_ce_kernel<<<KEMB / 4, 256, 0, stream>>>(cbg, Bhat, ce);
    gemm_argmin_kernel<<<dim3(KEMB / 128, NTOK / 128), 256, 0, stream>>>(Ahat, Bhat, ce, part);
    argmin_reduce_kernel<<<NTOK / 4, 256, 0, stream>>>(part, tokIdx, flist, flagCnt);
    refine_kernel<<<256, 256, 0, stream>>>(xg, cbg, part, tokIdx, flist, flagCnt);
    finalize_kernel<<<NTOK / 4, 256, 0, stream>>>(cbg, tokIdx, countsI, slotOf, quant, enc);
    scan_cs_kernel<<<1, 256, 0, stream>>>(countsI, ema_cs, offs, cs_pre, nptr);
    filllist_kernel<<<NTOK / 256, 256, 0, stream>>>(tokIdx, offs, slotOf, tlist);
    segdw_kernel<<<NTOK / SEG_CHUNK, 256, 0, stream>>>(xg, tlist, tokIdx, dw);
    epi_kernel<<<(KEMB * DDIM) / 256, 256, 0, stream>>>(ema_w, dw, cs_pre, nptr,
                                                        new_cb, new_w, cs_out);
}

// Round 2
// 804.311 us; speedup vs baseline: 1.0632x; 1.0382x over previous
//
#include <hip/hip_runtime.h>
#include <hip/hip_bf16.h>

#define NTOK 32768
#define KEMB 4096
#define DDIM 256
#define DECAYF 0.99f
#define EPSF 1e-5f
#define KSPLIT 256          // hi-only fp16: Xh . Ch, error handled by flag+refine
#define FLAG_THETA 0.09f    // ~5 sigma of hi-only distance-diff noise (0.018)
#define PRUNE_MARGIN 0.25f  // 2*theta + 6*sigma error bound for chunk pruning

// ---------------- workspace layout (BYTE offsets) ----------------
#define B_AHAT  0ull          // 32768*256 f16 = 16777216 B  Xh
#define B_BHAT  16777216ull   // 4096*256 f16  = 2097152 B   Ch
#define B_PART  18874368ull   // 32768*64 float4 = 33554432 B per-64col-chunk (b1,b2,idx)
#define B_CE    52428800ull   // 4096 f32
#define B_CNTI  52445184ull   // 4096 int: integer counts (atomic slot counters)
#define B_CSP   52461568ull   // 4096 f32: cs_pre
#define B_OFFS  52477952ull   // 4096 int: CSR offsets
#define B_NPTR  52494336ull   // f32 n (plain store by scan_cs; no memset needed)
#define B_TIDX  52494400ull   // 32768 int: per-token argmin
#define B_SLOT  52756544ull   // 32768 int: slot of token within its cluster
#define B_TLIST 52887616ull   // 32768 int: CSR token list
#define B_DW    53018688ull   // 4096*256 f32 = 4194304 B segment sums
// total ~57.2 MB

// ---------------- output layout (float offsets) ----------------
#define OFF_Q  0ull                 // quantized  [32768,256]
#define OFF_E  8388608ull           // encodings  [32768,4096]
#define OFF_CB 142606336ull         // new_codebook [4096,256]
#define OFF_W  143654912ull         // new_ema_w    [4096,256]
#define OFF_CS 144703488ull         // cs [4096]

typedef __attribute__((ext_vector_type(8))) _Float16 f16x8;
typedef __attribute__((ext_vector_type(4))) _Float16 f16x4;
typedef __attribute__((ext_vector_type(4))) float f32x4;

// ---- fused prep: X cast (blocks 0..4095), cb cast + norms (4096..5119),
// countsI zero (5120..5135), dw zero (5136..6159). One launch replaces
// two cast kernels + two small memsets.
__global__ __launch_bounds__(256) void prep_kernel(const float* __restrict__ xg,
                                                   const float* __restrict__ cbg,
                                                   _Float16* __restrict__ Ahat,
                                                   _Float16* __restrict__ Bhat,
                                                   float* __restrict__ ce,
                                                   int* __restrict__ countsI,
                                                   float4* __restrict__ dwv) {
    int b = blockIdx.x;
    int tid = threadIdx.x;
    if (b < 4096) {
        size_t gid = (size_t)b * 256 + tid;
        const float* sp = xg + gid * 8;
        f16x8 v;
        #pragma unroll
        for (int t = 0; t < 8; ++t) v[t] = (_Float16)sp[t];
        *(f16x8*)(Ahat + gid * 8) = v;
    } else if (b < 5120) {
        int k = (b - 4096) * 4 + (tid >> 6);
        int lane = tid & 63;
        float4 v = *(const float4*)(cbg + (size_t)k * DDIM + lane * 4);
        f16x4 h;
        h[0] = (_Float16)v.x; h[1] = (_Float16)v.y;
        h[2] = (_Float16)v.z; h[3] = (_Float16)v.w;
        *(f16x4*)(Bhat + (size_t)k * DDIM + lane * 4) = h;
        float s = v.x * v.x + v.y * v.y + v.z * v.z + v.w * v.w;
        #pragma unroll
        for (int o = 32; o > 0; o >>= 1) s += __shfl_down(s, o);
        if (lane == 0) ce[k] = s;
    } else if (b < 5136) {
        countsI[(b - 5120) * 256 + tid] = 0;
    } else {
        float4 z = {0.f, 0.f, 0.f, 0.f};
        dwv[(size_t)(b - 5136) * 256 + tid] = z;
    }
}

// ---- fp16 MFMA GEMM (M=32768, N=4096, K=256) with fused per-row argmin.
// R3-validated structure: 128x128 tile, BK=64, global_load_lds width-16,
// XOR-swizzled chunk staging -> conflict-free ds_read_b128.
// XCD-aware bijective chunk remap (8192 % 8 == 0): A-tile sharers co-XCD.
__global__ __launch_bounds__(256) void gemm_argmin_kernel(
        const _Float16* __restrict__ Ahat,
        const _Float16* __restrict__ Bhat,
        const float* __restrict__ ceg,
        float4* __restrict__ part) {
    __shared__ _Float16 As[128 * 64];   // 16 KB
    __shared__ _Float16 Bs[128 * 64];   // 16 KB
    const int tid  = threadIdx.x;
    const int lane = tid & 63;
    const int wave = tid >> 6;
    const int wm = wave >> 1, wn = wave & 1;  // 2x2 wave grid, 64x64 per wave

    int lin = blockIdx.y * 32 + blockIdx.x;
    lin = (lin & 7) * 1024 + (lin >> 3);      // bijective: 8192 = 8 * 1024
    const int nb = lin & 31, mb = lin >> 5;   // nb fast: A-tile sharers adjacent

    const int col = lane & 15, q = lane >> 4;
    const int cswz = q ^ (col & 7);           // reader chunk swizzle base

    const int srow = tid >> 3;
    const int sswz = (tid & 7) ^ (srow & 7);
    const _Float16* ag = Ahat + (size_t)(mb * 128 + srow) * KSPLIT + sswz * 8;
    const _Float16* bg = Bhat + (size_t)(nb * 128 + srow) * KSPLIT + sswz * 8;

    f32x4 zero = {0.f, 0.f, 0.f, 0.f};
    f32x4 acc[4][4];
    #pragma unroll
    for (int i = 0; i < 4; ++i)
        #pragma unroll
        for (int j = 0; j < 4; ++j) acc[i][j] = zero;

    for (int kt = 0; kt < KSPLIT / 64; ++kt) {
        __syncthreads();
        #pragma unroll
        for (int n = 0; n < 4; ++n) {
            __builtin_amdgcn_global_load_lds(
                (const __attribute__((address_space(1))) void*)(ag + (size_t)n * 32 * KSPLIT + kt * 64),
                (__attribute__((address_space(3))) void*)(As + n * 2048 + tid * 8), 16, 0, 0);
            __builtin_amdgcn_global_load_lds(
                (const __attribute__((address_space(1))) void*)(bg + (size_t)n * 32 * KSPLIT + kt * 64),
                (__attribute__((address_space(3))) void*)(Bs + n * 2048 + tid * 8), 16, 0, 0);
        }
        __syncthreads();

        const f16x8* Av = (const f16x8*)As;
        const f16x8* Bv = (const f16x8*)Bs;
        #pragma unroll
        for (int ks = 0; ks < 2; ++ks) {
            f16x8 a[4], b[4];
            #pragma unroll
            for (int i = 0; i < 4; ++i)
                a[i] = Av[(wm * 64 + i * 16 + col) * 8 + (cswz ^ (ks * 4))];
            #pragma unroll
            for (int j = 0; j < 4; ++j)
                b[j] = Bv[(wn * 64 + j * 16 + col) * 8 + (cswz ^ (ks * 4))];
            #pragma unroll
            for (int i = 0; i < 4; ++i)
                #pragma unroll
                for (int j = 0; j < 4; ++j)
                    acc[i][j] = __builtin_amdgcn_mfma_f32_16x16x32_f16(a[i], b[j], acc[i][j], 0, 0, 0);
        }
    }

    // epilogue: s = ||c||^2 - 2*dot. C/D layout: col = lane&15, row = q*4+reg.
    float ce_j[4];
    #pragma unroll
    for (int j = 0; j < 4; ++j) ce_j[j] = ceg[nb * 128 + wn * 64 + j * 16 + col];

    #pragma unroll
    for (int i = 0; i < 4; ++i) {
        #pragma unroll
        for (int r = 0; r < 4; ++r) {
            float b1 = 3.4e38f, b2 = 3.4e38f;
            int i1 = 0x7fffffff;
            #pragma unroll
            for (int j = 0; j < 4; ++j) {
                float s = ce_j[j] - 2.0f * acc[i][j][r];
                int n = nb * 128 + wn * 64 + j * 16 + col;
                if (s < b1) { b2 = b1; b1 = s; i1 = n; }
                else if (s < b2) { b2 = s; }
            }
            #pragma unroll
            for (int m = 1; m < 16; m <<= 1) {
                float ob1 = __shfl_xor(b1, m, 16);
                float ob2 = __shfl_xor(b2, m, 16);
                int   oi  = __shfl_xor(i1, m, 16);
                bool take = (ob1 < b1) || (ob1 == b1 && oi < i1);
                float nb2 = take ? fminf(b1, ob2) : fminf(b2, ob1);
                if (take) { b1 = ob1; i1 = oi; }
                b2 = nb2;
            }
            if (col == i * 4 + r) {   // unique writer lane per (q,i,r)
                int mrow = mb * 128 + wm * 64 + i * 16 + q * 4 + r;
                float4 p;
                p.x = b1; p.y = b2; p.z = __int_as_float(i1); p.w = 0.0f;
                part[(size_t)mrow * 64 + nb * 2 + wn] = p;
            }
        }
    }
}

// ---- fused post-process: one wave per token. Merges the old
// argmin_reduce + refine + finalize kernels:
//   (1) 64-chunk butterfly merge -> global (b1,b2,i1) on ALL lanes
//   (2) near-tie flag -> in-wave chunk-pruned fp64 refine (rare, wave-uniform)
//   (3) slot atomic + one-hot store (enc pre-zeroed) + quant row gather-copy
__global__ __launch_bounds__(256) void post_kernel(const float* __restrict__ xg,
                                                   const float* __restrict__ cb,
                                                   const float4* __restrict__ part,
                                                   int* __restrict__ tokIdx,
                                                   int* __restrict__ countsI,
                                                   int* __restrict__ slotOf,
                                                   float* __restrict__ quant,
                                                   float* __restrict__ enc) {
    int row = blockIdx.x * 4 + (threadIdx.x >> 6);
    int lane = threadIdx.x & 63;
    float4 p = part[(size_t)row * 64 + lane];
    float b1 = p.x, b2 = p.y;
    int i1 = __float_as_int(p.z);
    float cb1 = p.x;                       // this lane's chunk-best (for pruning)
    #pragma unroll
    for (int m = 1; m < 64; m <<= 1) {
        float ob1 = __shfl_xor(b1, m);
        float ob2 = __shfl_xor(b2, m);
        int   oi  = __shfl_xor(i1, m);
        bool take = (ob1 < b1) || (ob1 == b1 && oi < i1);
        float nb2 = take ? fminf(b1, ob2) : fminf(b2, ob1);
        if (take) { b1 = ob1; i1 = oi; }
        b2 = nb2;
    }
    // butterfly is symmetric: every lane now holds identical (b1,b2,i1).
    int kfin = i1;
    if (b2 - b1 < FLAG_THETA) {
        // chunk-pruned fp64 refine, wave-uniform branch. Chunks whose approx
        // best exceeds b1+PRUNE_MARGIN provably cannot hold the true argmin.
        unsigned long long mask = __ballot(cb1 <= b1 + PRUNE_MARGIN);
        double best = 1e300;
        int bi = 0x7fffffff;
        const float* xr = xg + (size_t)row * DDIM;
        while (mask) {
            int c = __ffsll(mask) - 1;
            mask &= mask - 1;
            int k = c * 64 + lane;
            const float* e = cb + (size_t)k * DDIM;
            double s = 0.0;
            for (int d4 = 0; d4 < DDIM / 4; ++d4) {
                float4 e4 = *(const float4*)(e + d4 * 4);
                float4 x4 = *(const float4*)(xr + d4 * 4);
                double e0 = (double)e4.x, e1 = (double)e4.y;
                double e2 = (double)e4.z, e3 = (double)e4.w;
                s += e0 * (e0 - 2.0 * (double)x4.x) + e1 * (e1 - 2.0 * (double)x4.y)
                   + e2 * (e2 - 2.0 * (double)x4.z) + e3 * (e3 - 2.0 * (double)x4.w);
            }
            if (s < best || (s == best && k < bi)) { best = s; bi = k; }
        }
        #pragma unroll
        for (int m = 1; m < 64; m <<= 1) {
            double ob = __shfl_xor(best, m);
            int   oi  = __shfl_xor(bi, m);
            if (ob < best || (ob == best && oi < bi)) { best = ob; bi = oi; }
        }
        kfin = bi;                          // uniform across lanes
    }
    if (lane == 0) {
        tokIdx[row] = kfin;
        slotOf[row] = atomicAdd(countsI + kfin, 1);
        enc[(size_t)row * KEMB + kfin] = 1.0f;
    }
    float4 e = *(const float4*)(cb + (size_t)kfin * DDIM + lane * 4);
    *(float4*)(quant + (size_t)row * DDIM + lane * 4) = e;
}

// ---- CSR pass 2 + cs: single block. Exclusive scan of countsI -> offs,
// cs_pre = ema_cs*decay + (1-decay)*counts, n = sum(cs_pre) (plain store).
__global__ __launch_bounds__(256) void scan_cs_kernel(const int* __restrict__ countsI,
                                                      const float* __restrict__ ema_cs,
                                                      int* __restrict__ offs,
                                                      float* __restrict__ cs_pre,
                                                      float* __restrict__ nptr) {
    __shared__ int part[256];
    __shared__ float npart[256];
    __shared__ int pref[257];
    int tid = threadIdx.x;
    int local[16];
    int s = 0;
    float ns = 0.0f;
    #pragma unroll
    for (int i = 0; i < 16; ++i) {
        int c = countsI[tid * 16 + i];
        local[i] = c;
        s += c;
        float csp = ema_cs[tid * 16 + i] * DECAYF + (1.0f - DECAYF) * (float)c;
        cs_pre[tid * 16 + i] = csp;
        ns += csp;
    }
    part[tid] = s;
    npart[tid] = ns;
    __syncthreads();
    if (tid == 0) {
        pref[0] = 0;
        float nn = 0.0f;
        for (int i = 0; i < 256; ++i) {
            pref[i + 1] = pref[i] + part[i];
            nn += npart[i];
        }
        nptr[0] = nn;
    }
    __syncthreads();
    int run = pref[tid];
    #pragma unroll
    for (int i = 0; i < 16; ++i) { offs[tid * 16 + i] = run; run += local[i]; }
}

// ---- CSR pass 3: fill token list (no atomics) ----
__global__ __launch_bounds__(256) void filllist_kernel(const int* __restrict__ tokIdx,
                                                       const int* __restrict__ offs,
                                                       const int* __restrict__ slotOf,
                                                       int* __restrict__ tlist) {
    int t = blockIdx.x * 256 + threadIdx.x;
    int k = tokIdx[t];
    tlist[offs[k] + slotOf[t]] = t;
}

// ---- balanced segmented dw reduction over the CSR list ----
#define SEG_CHUNK 32
__global__ __launch_bounds__(256) void segdw_kernel(const float* __restrict__ xg,
                                                    const int* __restrict__ tlist,
                                                    const int* __restrict__ tokIdx,
                                                    float* __restrict__ dw) {
    int tid = threadIdx.x;
    int s0 = blockIdx.x * SEG_CHUNK;
    float acc = 0.0f;
    int curk = -1;
    for (int s = s0; s < s0 + SEG_CHUNK; ++s) {
        int t = tlist[s];
        int k = tokIdx[t];
        if (k != curk) {
            if (curk >= 0) atomicAdd(dw + (size_t)curk * DDIM + tid, acc);
            acc = 0.0f;
            curk = k;
        }
        acc += xg[(size_t)t * DDIM + tid];
    }
    if (curk >= 0) atomicAdd(dw + (size_t)curk * DDIM + tid, acc);
}

// ---- epilogue: new_ema_w, laplace-smoothed cs, new_codebook ----
__global__ __launch_bounds__(256) void epi_kernel(const float* __restrict__ ema_w,
                                                  const float* __restrict__ dw,
                                                  const float* __restrict__ cs_pre,
                                                  const float* __restrict__ nptr,
                                                  float* __restrict__ new_cb,
                                                  float* __restrict__ new_w,
                                                  float* __restrict__ cs_out) {
    int gid = blockIdx.x * 256 + threadIdx.x;   // 0 .. 1048575
    int k = gid >> 8, d = gid & 255;
    float n = *nptr;
    float csp = cs_pre[k];
    float cs = (csp + EPSF) / (n + (float)KEMB * EPSF) * n;
    float w = ema_w[gid] * DECAYF + (1.0f - DECAYF) * dw[gid];
    new_w[gid] = w;
    new_cb[gid] = w / cs;
    if (d == 0) cs_out[k] = cs;
}

extern "C" void kernel_launch(void* const* d_in, const int* in_sizes, int n_in,
                              void* d_out, int out_size, void* d_ws, size_t ws_size,
                              hipStream_t stream) {
    const float* xg     = (const float*)d_in[0];   // [32768,256]
    const float* cbg    = (const float*)d_in[1];   // [4096,256]
    const float* ema_w  = (const float*)d_in[2];   // [4096,256]
    const float* ema_cs = (const float*)d_in[3];   // [4096]

    float* out = (float*)d_out;
    unsigned char* wsb = (unsigned char*)d_ws;

    float* quant  = out + OFF_Q;
    float* enc    = out + OFF_E;
    float* new_cb = out + OFF_CB;
    float* new_w  = out + OFF_W;
    float* cs_out = out + OFF_CS;

    _Float16* Ahat = (_Float16*)(wsb + B_AHAT);
    _Float16* Bhat = (_Float16*)(wsb + B_BHAT);
    float4* part   = (float4*)(wsb + B_PART);
    float* ce      = (float*)(wsb + B_CE);
    int*   countsI = (int*)(wsb + B_CNTI);
    float* cs_pre  = (float*)(wsb + B_CSP);
    int*   offs    = (int*)(wsb + B_OFFS);
    float* nptr    = (float*)(wsb + B_NPTR);
    int*   tokIdx  = (int*)(wsb + B_TIDX);
    int*   slotOf  = (int*)(wsb + B_SLOT);
    int*   tlist   = (int*)(wsb + B_TLIST);
    float* dw      = (float*)(wsb + B_DW);

    // enc zeroed by the fill engine (~6.3 TB/s measured on this part);
    // post_kernel writes only the 32768 one-hot elements. countsI/dw zeroed
    // inside prep_kernel; nptr is plain-stored by scan_cs (no memset).
    hipMemsetAsync(enc, 0, (size_t)NTOK * KEMB * sizeof(float), stream);

    prep_kernel<<<6160, 256, 0, stream>>>(xg, cbg, Ahat, Bhat, ce, countsI, (float4*)dw);
    gemm_argmin_kernel<<<dim3(KEMB / 128, NTOK / 128), 256, 0, stream>>>(Ahat, Bhat, ce, part);
    post_kernel<<<NTOK / 4, 256, 0, stream>>>(xg, cbg, part, tokIdx, countsI, slotOf, quant, enc);
    scan_cs_kernel<<<1, 256, 0, stream>>>(countsI, ema_cs, offs, cs_pre, nptr);
    filllist_kernel<<<NTOK / 256, 256, 0, stream>>>(tokIdx, offs, slotOf, tlist);
    segdw_kernel<<<NTOK / SEG_CHUNK, 256, 0, stream>>>(xg, tlist, tokIdx, dw);
    epi_kernel<<<(KEMB * DDIM) / 256, 256, 0, stream>>>(ema_w, dw, cs_pre, nptr,
                                                        new_cb, new_w, cs_out);
}

// Round 3
// 797.501 us; speedup vs baseline: 1.0723x; 1.0085x over previous
//
#include <hip/hip_runtime.h>
#include <hip/hip_bf16.h>

#define NTOK 32768
#define KEMB 4096
#define DDIM 256
#define DECAYF 0.99f
#define EPSF 1e-5f
#define KSPLIT 256          // hi-only fp16: Xh . Ch, error handled by flag+refine
#define FLAG_THETA 0.11f    // 5-sigma fp16 noise (0.09) + 6-bit idx-pack noise (0.016)
#define PRUNE_MARGIN 0.28f  // 2*theta + 6*sigma error bound + pack noise
#define SBIAS 4096.0f       // positivity bias so packed-float order == value order

// ---------------- workspace layout (BYTE offsets) ----------------
#define B_AHAT  0ull          // 32768*256 f16 = 16777216 B  Xh
#define B_BHAT  16777216ull   // 4096*256 f16  = 2097152 B   Ch
#define B_PART  18874368ull   // 32768*64 float2 = 16777216 B per-64col-chunk (b1|idx, b2)
#define B_CE    52428800ull   // 4096 f32
#define B_CNTI  52445184ull   // 4096 int: integer counts (atomic slot counters)
#define B_CSP   52461568ull   // 4096 f32: cs_pre
#define B_OFFS  52477952ull   // 4096 int: CSR offsets (atomically consumed by filllist)
#define B_NPTR  52494336ull   // f32 n (plain store by scan_cs; no memset needed)
#define B_TIDX  52494400ull   // 32768 int: per-token argmin
#define B_TLIST 52887616ull   // 32768 int: CSR token list
#define B_DW    53018688ull   // 4096*256 f32 = 4194304 B segment sums
// total ~57.2 MB

// ---------------- output layout (float offsets) ----------------
#define OFF_Q  0ull                 // quantized  [32768,256]
#define OFF_E  8388608ull           // encodings  [32768,4096]
#define OFF_CB 142606336ull         // new_codebook [4096,256]
#define OFF_W  143654912ull         // new_ema_w    [4096,256]
#define OFF_CS 144703488ull         // cs [4096]

typedef __attribute__((ext_vector_type(8))) _Float16 f16x8;
typedef __attribute__((ext_vector_type(4))) _Float16 f16x4;
typedef __attribute__((ext_vector_type(4))) float f32x4;

// ---- fused prep: X cast (blocks 0..4095), cb cast + norms (4096..5119),
// countsI zero (5120..5135), dw zero (5136..6159).
__global__ __launch_bounds__(256) void prep_kernel(const float* __restrict__ xg,
                                                   const float* __restrict__ cbg,
                                                   _Float16* __restrict__ Ahat,
                                                   _Float16* __restrict__ Bhat,
                                                   float* __restrict__ ce,
                                                   int* __restrict__ countsI,
                                                   float4* __restrict__ dwv) {
    int b = blockIdx.x;
    int tid = threadIdx.x;
    if (b < 4096) {
        size_t gid = (size_t)b * 256 + tid;
        const float* sp = xg + gid * 8;
        f16x8 v;
        #pragma unroll
        for (int t = 0; t < 8; ++t) v[t] = (_Float16)sp[t];
        *(f16x8*)(Ahat + gid * 8) = v;
    } else if (b < 5120) {
        int k = (b - 4096) * 4 + (tid >> 6);
        int lane = tid & 63;
        float4 v = *(const float4*)(cbg + (size_t)k * DDIM + lane * 4);
        f16x4 h;
        h[0] = (_Float16)v.x; h[1] = (_Float16)v.y;
        h[2] = (_Float16)v.z; h[3] = (_Float16)v.w;
        *(f16x4*)(Bhat + (size_t)k * DDIM + lane * 4) = h;
        float s = v.x * v.x + v.y * v.y + v.z * v.z + v.w * v.w;
        #pragma unroll
        for (int o = 32; o > 0; o >>= 1) s += __shfl_down(s, o);
        if (lane == 0) ce[k] = s;
    } else if (b < 5136) {
        countsI[(b - 5120) * 256 + tid] = 0;
    } else {
        float4 z = {0.f, 0.f, 0.f, 0.f};
        dwv[(size_t)(b - 5136) * 256 + tid] = z;
    }
}

// ---- fp16 MFMA GEMM (M=32768, N=4096, K=256) with fused per-row argmin.
// 128x128 tile, BK=64, global_load_lds width-16, XOR-swizzled staging,
// XCD-aware bijective remap. Epilogue packs chunk-local idx (6 bits) into
// the biased distance's mantissa LSBs -> 2-value butterfly, float2 part.
__global__ __launch_bounds__(256) void gemm_argmin_kernel(
        const _Float16* __restrict__ Ahat,
        const _Float16* __restrict__ Bhat,
        const float* __restrict__ ceg,
        float2* __restrict__ part) {
    __shared__ _Float16 As[128 * 64];   // 16 KB
    __shared__ _Float16 Bs[128 * 64];   // 16 KB
    const int tid  = threadIdx.x;
    const int lane = tid & 63;
    const int wave = tid >> 6;
    const int wm = wave >> 1, wn = wave & 1;  // 2x2 wave grid, 64x64 per wave

    int lin = blockIdx.y * 32 + blockIdx.x;
    lin = (lin & 7) * 1024 + (lin >> 3);      // bijective: 8192 = 8 * 1024
    const int nb = lin & 31, mb = lin >> 5;   // nb fast: A-tile sharers adjacent

    const int col = lane & 15, q = lane >> 4;
    const int cswz = q ^ (col & 7);           // reader chunk swizzle base

    const int srow = tid >> 3;
    const int sswz = (tid & 7) ^ (srow & 7);
    const _Float16* ag = Ahat + (size_t)(mb * 128 + srow) * KSPLIT + sswz * 8;
    const _Float16* bg = Bhat + (size_t)(nb * 128 + srow) * KSPLIT + sswz * 8;

    f32x4 zero = {0.f, 0.f, 0.f, 0.f};
    f32x4 acc[4][4];
    #pragma unroll
    for (int i = 0; i < 4; ++i)
        #pragma unroll
        for (int j = 0; j < 4; ++j) acc[i][j] = zero;

    for (int kt = 0; kt < KSPLIT / 64; ++kt) {
        __syncthreads();
        #pragma unroll
        for (int n = 0; n < 4; ++n) {
            __builtin_amdgcn_global_load_lds(
                (const __attribute__((address_space(1))) void*)(ag + (size_t)n * 32 * KSPLIT + kt * 64),
                (__attribute__((address_space(3))) void*)(As + n * 2048 + tid * 8), 16, 0, 0);
            __builtin_amdgcn_global_load_lds(
                (const __attribute__((address_space(1))) void*)(bg + (size_t)n * 32 * KSPLIT + kt * 64),
                (__attribute__((address_space(3))) void*)(Bs + n * 2048 + tid * 8), 16, 0, 0);
        }
        __syncthreads();

        const f16x8* Av = (const f16x8*)As;
        const f16x8* Bv = (const f16x8*)Bs;
        #pragma unroll
        for (int ks = 0; ks < 2; ++ks) {
            f16x8 a[4], b[4];
            #pragma unroll
            for (int i = 0; i < 4; ++i)
                a[i] = Av[(wm * 64 + i * 16 + col) * 8 + (cswz ^ (ks * 4))];
            #pragma unroll
            for (int j = 0; j < 4; ++j)
                b[j] = Bv[(wn * 64 + j * 16 + col) * 8 + (cswz ^ (ks * 4))];
            #pragma unroll
            for (int i = 0; i < 4; ++i)
                #pragma unroll
                for (int j = 0; j < 4; ++j)
                    acc[i][j] = __builtin_amdgcn_mfma_f32_16x16x32_f16(a[i], b[j], acc[i][j], 0, 0, 0);
        }
    }

    // epilogue: s = ||c||^2 - 2*dot + SBIAS (positive), pack local idx into
    // low 6 mantissa bits -> min on packed floats == min-with-tiebreak.
    float ce_j[4];
    #pragma unroll
    for (int j = 0; j < 4; ++j) ce_j[j] = ceg[nb * 128 + wn * 64 + j * 16 + col];

    #pragma unroll
    for (int i = 0; i < 4; ++i) {
        #pragma unroll
        for (int r = 0; r < 4; ++r) {
            float p1 = 3.4e38f, p2 = 3.4e38f;
            #pragma unroll
            for (int j = 0; j < 4; ++j) {
                float s = ce_j[j] - 2.0f * acc[i][j][r] + SBIAS;
                int loc = j * 16 + col;                  // 6-bit chunk-local idx
                float sp = __int_as_float((__float_as_int(s) & ~63) | loc);
                if (sp < p1) { p2 = p1; p1 = sp; }
                else if (sp < p2) { p2 = sp; }
            }
            #pragma unroll
            for (int m = 1; m < 16; m <<= 1) {
                float o1 = __shfl_xor(p1, m, 16);
                float o2 = __shfl_xor(p2, m, 16);
                float lo = fminf(p1, o1);
                float hi = fmaxf(p1, o1);
                p2 = fminf(hi, fminf(p2, o2));
                p1 = lo;
            }
            if (col == i * 4 + r) {   // unique writer lane per (q,i,r)
                int mrow = mb * 128 + wm * 64 + i * 16 + q * 4 + r;
                float2 p;
                p.x = p1; p.y = p2;
                part[(size_t)mrow * 64 + nb * 2 + wn] = p;
            }
        }
    }
}

// ---- fused post-process: one wave per token.
//   (1) 64-chunk 2-value butterfly merge (packed floats)
//   (2) near-tie -> in-wave chunk-pruned fp64 refine (exact, incl. ties)
//   (3) count atomic + FULL one-hot enc row write + quant row gather-copy
__global__ __launch_bounds__(256) void post_kernel(const float* __restrict__ xg,
                                                   const float* __restrict__ cb,
                                                   const float2* __restrict__ part,
                                                   int* __restrict__ tokIdx,
                                                   int* __restrict__ countsI,
                                                   float* __restrict__ quant,
                                                   float* __restrict__ enc) {
    int row = blockIdx.x * 4 + (threadIdx.x >> 6);
    int lane = threadIdx.x & 63;
    float2 p = part[(size_t)row * 64 + lane];
    float own = p.x;                       // this lane's chunk-best (packed)
    float b1 = p.x, b2 = p.y;
    #pragma unroll
    for (int m = 1; m < 64; m <<= 1) {
        float o1 = __shfl_xor(b1, m);
        float o2 = __shfl_xor(b2, m);
        float lo = fminf(b1, o1);
        float hi = fmaxf(b1, o1);
        b2 = fminf(hi, fminf(b2, o2));
        b1 = lo;
    }
    // every lane now holds identical (b1,b2). Winner chunk = lowest lane
    // whose own packed best equals the global best (lowest lane -> lowest
    // global idx among packed-equal ties, which share the same local idx).
    int kfin;
    {
        unsigned long long wmask = __ballot(own == b1);
        int wl = __ffsll(wmask) - 1;
        kfin = wl * 64 + (__float_as_int(b1) & 63);
    }
    if (b2 - b1 < FLAG_THETA) {
        // chunk-pruned fp64 refine, wave-uniform branch (exact tie-breaks).
        unsigned long long mask = __ballot(own <= b1 + PRUNE_MARGIN);
        double best = 1e300;
        int bi = 0x7fffffff;
        const float* xr = xg + (size_t)row * DDIM;
        while (mask) {
            int c = __ffsll(mask) - 1;
            mask &= mask - 1;
            int k = c * 64 + lane;
            const float* e = cb + (size_t)k * DDIM;
            double s = 0.0;
            for (int d4 = 0; d4 < DDIM / 4; ++d4) {
                float4 e4 = *(const float4*)(e + d4 * 4);
                float4 x4 = *(const float4*)(xr + d4 * 4);
                double e0 = (double)e4.x, e1 = (double)e4.y;
                double e2 = (double)e4.z, e3 = (double)e4.w;
                s += e0 * (e0 - 2.0 * (double)x4.x) + e1 * (e1 - 2.0 * (double)x4.y)
                   + e2 * (e2 - 2.0 * (double)x4.z) + e3 * (e3 - 2.0 * (double)x4.w);
            }
            if (s < best || (s == best && k < bi)) { best = s; bi = k; }
        }
        #pragma unroll
        for (int m = 1; m < 64; m <<= 1) {
            double ob = __shfl_xor(best, m);
            int   oi  = __shfl_xor(bi, m);
            if (ob < best || (ob == best && oi < bi)) { best = ob; bi = oi; }
        }
        kfin = bi;                          // uniform across lanes
    }
    if (lane == 0) {
        tokIdx[row] = kfin;
        atomicAdd(countsI + kfin, 1);
    }
    // full one-hot enc row (replaces the 537 MB memset dispatch; overlaps
    // the butterfly/refine latency of neighboring waves).
    {
        float4* er = (float4*)(enc + (size_t)row * KEMB);
        int kf4 = kfin >> 2, kc = kfin & 3;
        #pragma unroll
        for (int v = 0; v < 16; ++v) {
            int f4 = v * 64 + lane;
            float4 val = {0.f, 0.f, 0.f, 0.f};
            if (f4 == kf4) ((float*)&val)[kc] = 1.0f;
            er[f4] = val;
        }
    }
    float4 e = *(const float4*)(cb + (size_t)kfin * DDIM + lane * 4);
    *(float4*)(quant + (size_t)row * DDIM + lane * 4) = e;
}

// ---- CSR pass 2 + cs: single block. Exclusive scan of countsI -> offs,
// cs_pre = ema_cs*decay + (1-decay)*counts, n = sum(cs_pre) (plain store).
__global__ __launch_bounds__(256) void scan_cs_kernel(const int* __restrict__ countsI,
                                                      const float* __restrict__ ema_cs,
                                                      int* __restrict__ offs,
                                                      float* __restrict__ cs_pre,
                                                      float* __restrict__ nptr) {
    __shared__ int part[256];
    __shared__ float npart[256];
    __shared__ int pref[257];
    int tid = threadIdx.x;
    int local[16];
    int s = 0;
    float ns = 0.0f;
    #pragma unroll
    for (int i = 0; i < 16; ++i) {
        int c = countsI[tid * 16 + i];
        local[i] = c;
        s += c;
        float csp = ema_cs[tid * 16 + i] * DECAYF + (1.0f - DECAYF) * (float)c;
        cs_pre[tid * 16 + i] = csp;
        ns += csp;
    }
    part[tid] = s;
    npart[tid] = ns;
    __syncthreads();
    if (tid == 0) {
        pref[0] = 0;
        float nn = 0.0f;
        for (int i = 0; i < 256; ++i) {
            pref[i + 1] = pref[i] + part[i];
            nn += npart[i];
        }
        nptr[0] = nn;
    }
    __syncthreads();
    int run = pref[tid];
    #pragma unroll
    for (int i = 0; i < 16; ++i) { offs[tid * 16 + i] = run; run += local[i]; }
}

// ---- CSR pass 3: fill token list. offs doubles as the slot cursor
// (atomically bumped; nothing reads offs afterwards).
__global__ __launch_bounds__(256) void filllist_kernel(const int* __restrict__ tokIdx,
                                                       int* __restrict__ offs,
                                                       int* __restrict__ tlist) {
    int t = blockIdx.x * 256 + threadIdx.x;
    int k = tokIdx[t];
    int slot = atomicAdd(offs + k, 1);
    tlist[slot] = t;
}

// ---- balanced segmented dw reduction over the CSR list ----
#define SEG_CHUNK 32
__global__ __launch_bounds__(256) void segdw_kernel(const float* __restrict__ xg,
                                                    const int* __restrict__ tlist,
                                                    const int* __restrict__ tokIdx,
                                                    float* __restrict__ dw) {
    int tid = threadIdx.x;
    int s0 = blockIdx.x * SEG_CHUNK;
    float acc = 0.0f;
    int curk = -1;
    for (int s = s0; s < s0 + SEG_CHUNK; ++s) {
        int t = tlist[s];
        int k = tokIdx[t];
        if (k != curk) {
            if (curk >= 0) atomicAdd(dw + (size_t)curk * DDIM + tid, acc);
            acc = 0.0f;
            curk = k;
        }
        acc += xg[(size_t)t * DDIM + tid];
    }
    if (curk >= 0) atomicAdd(dw + (size_t)curk * DDIM + tid, acc);
}

// ---- epilogue: new_ema_w, laplace-smoothed cs, new_codebook ----
__global__ __launch_bounds__(256) void epi_kernel(const float* __restrict__ ema_w,
                                                  const float* __restrict__ dw,
                                                  const float* __restrict__ cs_pre,
                                                  const float* __restrict__ nptr,
                                                  float* __restrict__ new_cb,
                                                  float* __restrict__ new_w,
                                                  float* __restrict__ cs_out) {
    int gid = blockIdx.x * 256 + threadIdx.x;   // 0 .. 1048575
    int k = gid >> 8, d = gid & 255;
    float n = *nptr;
    float csp = cs_pre[k];
    float cs = (csp + EPSF) / (n + (float)KEMB * EPSF) * n;
    float w = ema_w[gid] * DECAYF + (1.0f - DECAYF) * dw[gid];
    new_w[gid] = w;
    new_cb[gid] = w / cs;
    if (d == 0) cs_out[k] = cs;
}

extern "C" void kernel_launch(void* const* d_in, const int* in_sizes, int n_in,
                              void* d_out, int out_size, void* d_ws, size_t ws_size,
                              hipStream_t stream) {
    const float* xg     = (const float*)d_in[0];   // [32768,256]
    const float* cbg    = (const float*)d_in[1];   // [4096,256]
    const float* ema_w  = (const float*)d_in[2];   // [4096,256]
    const float* ema_cs = (const float*)d_in[3];   // [4096]

    float* out = (float*)d_out;
    unsigned char* wsb = (unsigned char*)d_ws;

    float* quant  = out + OFF_Q;
    float* enc    = out + OFF_E;
    float* new_cb = out + OFF_CB;
    float* new_w  = out + OFF_W;
    float* cs_out = out + OFF_CS;

    _Float16* Ahat = (_Float16*)(wsb + B_AHAT);
    _Float16* Bhat = (_Float16*)(wsb + B_BHAT);
    float2* part   = (float2*)(wsb + B_PART);
    float* ce      = (float*)(wsb + B_CE);
    int*   countsI = (int*)(wsb + B_CNTI);
    float* cs_pre  = (float*)(wsb + B_CSP);
    int*   offs    = (int*)(wsb + B_OFFS);
    float* nptr    = (float*)(wsb + B_NPTR);
    int*   tokIdx  = (int*)(wsb + B_TIDX);
    int*   tlist   = (int*)(wsb + B_TLIST);
    float* dw      = (float*)(wsb + B_DW);

    // No memsets: enc rows fully written by post_kernel; countsI/dw zeroed
    // in prep_kernel; nptr plain-stored by scan_cs.
    prep_kernel<<<6160, 256, 0, stream>>>(xg, cbg, Ahat, Bhat, ce, countsI, (float4*)dw);
    gemm_argmin_kernel<<<dim3(KEMB / 128, NTOK / 128), 256, 0, stream>>>(Ahat, Bhat, ce, part);
    post_kernel<<<NTOK / 4, 256, 0, stream>>>(xg, cbg, part, tokIdx, countsI, quant, enc);
    scan_cs_kernel<<<1, 256, 0, stream>>>(countsI, ema_cs, offs, cs_pre, nptr);
    filllist_kernel<<<NTOK / 256, 256, 0, stream>>>(tokIdx, offs, tlist);
    segdw_kernel<<<NTOK / SEG_CHUNK, 256, 0, stream>>>(xg, tlist, tokIdx, dw);
    epi_kernel<<<(KEMB * DDIM) / 256, 256, 0, stream>>>(ema_w, dw, cs_pre, nptr,
                                                        new_cb, new_w, cs_out);
}